// Round 5
// baseline (1672.228 us; speedup 1.0000x reference)
//
#include <hip/hip_runtime.h>
#include <cstdint>
#include <cstddef>

// Problem constants (from reference)
#define BATCH 4096
#define NCH 10
#define FEAT 2048
#define NOUT 2048
#define MROWS (BATCH * NCH)   // 40960
#define KP 6144               // 3*FEAT for bf16x3 split GEMM (K'-interleaved)
#define NTILES 96             // KP/64
#define BN_EPS 1e-3f

using u16 = unsigned short;
typedef __attribute__((ext_vector_type(8))) short bf16x8;
typedef __attribute__((ext_vector_type(8))) unsigned short u16x8;
typedef __attribute__((ext_vector_type(4))) float f32x4;

// ---------- bf16 split helpers (manual RNE) ----------
__device__ __forceinline__ u16 f2bf(float f) {
  uint32_t u = __float_as_uint(f);
  u += 0x7FFFu + ((u >> 16) & 1u);
  return (u16)(u >> 16);
}
__device__ __forceinline__ float bf2f(u16 h) {
  return __uint_as_float(((uint32_t)h) << 16);
}

// ---------- async global->LDS, 16B per lane ----------
__device__ __forceinline__ void gload16(const u16* g, u16* l) {
  __builtin_amdgcn_global_load_lds(
      (const __attribute__((address_space(1))) void*)g,
      (__attribute__((address_space(3))) void*)l, 16, 0, 0);
}

#define BAR() __builtin_amdgcn_s_barrier()
#define VMW4() asm volatile("s_waitcnt vmcnt(4)" ::: "memory")
#define VMW0() asm volatile("s_waitcnt vmcnt(0)" ::: "memory")

// ---------- prep: W [K][N] fp32 -> Bt [N][KP] bf16, K'-interleaved (hi,hi,lo per 64-k) ----------
__global__ void prep_b_kernel(const float* __restrict__ W, u16* __restrict__ bt) {
  __shared__ float tile[32][33];
  int tx = threadIdx.x, ty = threadIdx.y;     // 32 x 8
  int n0 = blockIdx.x * 32, k0 = blockIdx.y * 32;
#pragma unroll
  for (int r = 0; r < 4; ++r)
    tile[ty + 8 * r][tx] = W[(size_t)(k0 + ty + 8 * r) * NOUT + n0 + tx];
  __syncthreads();
#pragma unroll
  for (int r = 0; r < 4; ++r) {
    int n = n0 + ty + 8 * r;
    int k = k0 + tx;
    float v = tile[tx][ty + 8 * r];
    u16 hi = f2bf(v);
    u16 lo = f2bf(v - bf2f(hi));
    int g = k >> 6, kc = k & 63;
    size_t base = (size_t)n * KP + (size_t)(3 * g) * 64 + kc;
    bt[base] = hi;          // tile 3g   : pairs xh  (hi*Whi)
    bt[base + 64] = hi;     // tile 3g+1 : pairs xl  (lo*Whi)
    bt[base + 128] = lo;    // tile 3g+2 : pairs xh  (hi*Wlo)
  }
}

// ---------- premix (adjn fused): xm[b][i][f] = sum_j adjn[i][j]*x[b][j][f] -> hi/lo bf16 ----------
__global__ void __launch_bounds__(256) premix_kernel(const float* __restrict__ x,
                                                     const float* __restrict__ adj,
                                                     u16* __restrict__ xh, u16* __restrict__ xl) {
  __shared__ float A[NCH * NCH];
  int t = threadIdx.x;
  if (t < NCH * NCH) {
    int i = t / NCH, j = t % NCH;
    float di = 0.f, dj = 0.f;
#pragma unroll
    for (int q = 0; q < NCH; ++q) {
      di += fabsf(adj[i * NCH + q]);
      dj += fabsf(adj[j * NCH + q]);
    }
    di = fmaxf(di, 1e-8f);
    dj = fmaxf(dj, 1e-8f);
    A[t] = adj[i * NCH + j] * rsqrtf(di * dj) + (i == j ? 1.f : 0.f);
  }
  __syncthreads();
  int b = blockIdx.x;
  const float* xb = x + (size_t)b * (NCH * FEAT);
  u16* xhb = xh + (size_t)b * (NCH * FEAT);
  u16* xlb = xl + (size_t)b * (NCH * FEAT);
  float4 v[NCH][2];
#pragma unroll
  for (int j = 0; j < NCH; ++j) {
    const float4* xp = (const float4*)(xb + j * FEAT + t * 8);
    v[j][0] = xp[0];
    v[j][1] = xp[1];
  }
#pragma unroll
  for (int i = 0; i < NCH; ++i) {
    float o[8] = {0.f, 0.f, 0.f, 0.f, 0.f, 0.f, 0.f, 0.f};
#pragma unroll
    for (int j = 0; j < NCH; ++j) {
      float a = A[i * NCH + j];
      o[0] = fmaf(a, v[j][0].x, o[0]);
      o[1] = fmaf(a, v[j][0].y, o[1]);
      o[2] = fmaf(a, v[j][0].z, o[2]);
      o[3] = fmaf(a, v[j][0].w, o[3]);
      o[4] = fmaf(a, v[j][1].x, o[4]);
      o[5] = fmaf(a, v[j][1].y, o[5]);
      o[6] = fmaf(a, v[j][1].z, o[6]);
      o[7] = fmaf(a, v[j][1].w, o[7]);
    }
    u16x8 hv, lv;
#pragma unroll
    for (int e = 0; e < 8; ++e) {
      u16 h = f2bf(o[e]);
      hv[e] = h;
      lv[e] = f2bf(o[e] - bf2f(h));
    }
    *(u16x8*)(xhb + i * FEAT + t * 8) = hv;
    *(u16x8*)(xlb + i * FEAT + t * 8) = lv;
  }
}

// ---------- stage one half-tile (128 rows x 64 cols bf16 = 16 KB) via global_load_lds ----------
// LDS dest is wave-uniform base (+ implicit lane*16B); global source col-chunk pre-XOR'd (T2).
__device__ __forceinline__ void stage_half(const u16* __restrict__ src, int rstride,
                                           int grow0, int gcol0, u16* ldsbase,
                                           int w, int l) {
  int c0 = w * 64 + l;
  int r0 = c0 >> 3, cc0 = ((c0 & 7) ^ (r0 & 7)) << 3;
  gload16(src + (size_t)(grow0 + r0) * rstride + gcol0 + cc0, ldsbase + w * 512);
  int c1 = 512 + c0;
  int r1 = c1 >> 3, cc1 = ((c1 & 7) ^ (r1 & 7)) << 3;
  gload16(src + (size_t)(grow0 + r1) * rstride + gcol0 + cc1, ldsbase + 4096 + w * 512);
}

// ---------- one phase: [Q==0: read B-frags] + read A-quad Q + stage + bar + 16 MFMA + bar ----------
template <int Q, class StageFn>
__device__ __forceinline__ void do_phase(const u16* __restrict__ Abuf,
                                         const u16* __restrict__ Bbuf,
                                         f32x4 (&acc)[8][4], bf16x8 (&bfr)[4][2],
                                         int wr, int wc, int l15, int l4,
                                         StageFn stage, bool vm4, bool vm0) {
  if (Q == 0) {
#pragma unroll
    for (int nf = 0; nf < 4; ++nf)
#pragma unroll
      for (int kh = 0; kh < 2; ++kh) {
        int row = wc * 64 + nf * 16 + l15;
        bfr[nf][kh] = *(const bf16x8*)&Bbuf[row * 64 + (((kh * 4 + l4) ^ (row & 7)) << 3)];
      }
  }
  bf16x8 af[2][2];
#pragma unroll
  for (int mi = 0; mi < 2; ++mi)
#pragma unroll
    for (int kh = 0; kh < 2; ++kh) {
      int row = wr * 128 + (Q * 2 + mi) * 16 + l15;
      af[mi][kh] = *(const bf16x8*)&Abuf[row * 64 + (((kh * 4 + l4) ^ (row & 7)) << 3)];
    }
  stage();
  BAR();
  __builtin_amdgcn_s_setprio(1);
#pragma unroll
  for (int mi = 0; mi < 2; ++mi)
#pragma unroll
    for (int nf = 0; nf < 4; ++nf)
#pragma unroll
      for (int kh = 0; kh < 2; ++kh)
        acc[Q * 2 + mi][nf] = __builtin_amdgcn_mfma_f32_16x16x32_bf16(
            af[mi][kh], bfr[nf][kh], acc[Q * 2 + mi][nf], 0, 0, 0);
  __builtin_amdgcn_s_setprio(0);
  if (vm4) VMW4();
  if (vm0) VMW0();
  BAR();
}

// ---------- main GEMM: 256x256 tile, BK=64, 8 waves (2x4), 8-phase counted-vmcnt pipeline ----------
__global__ void __launch_bounds__(512, 2) gemm_kernel(
    const u16* __restrict__ xh, const u16* __restrict__ xl,
    const u16* __restrict__ bt, const float* __restrict__ bias,
    const float* __restrict__ gamma, const float* __restrict__ beta,
    const float* __restrict__ mean, const float* __restrict__ var,
    float* __restrict__ out) {
  __shared__ __align__(16) u16 sA[2][16384];   // 2 x 32 KB (256 rows x 64 cols)
  __shared__ __align__(16) u16 sB[2][16384];   // 2 x 32 KB
  const int tid = threadIdx.x;
  const int w = tid >> 6, l = tid & 63;
  const int wr = w >> 2, wc = w & 3;           // 2x4 wave grid; wave owns 128x64 output
  const int l15 = l & 15, l4 = l >> 4;
  // XCD chunk swizzle: 1280 blocks, 160/XCD, n-fast within chunk (bijective: 1280%8==0)
  const int wg = blockIdx.x;
  const int swz = (wg & 7) * 160 + (wg >> 3);
  const int m0 = (swz >> 3) * 256;             // 160 m-tiles
  const int n0 = (swz & 7) * 256;              // 8 n-tiles

  // A-source select per K'-tile t: t%3==1 -> xl else xh; col (t/3)*64  (K'-interleaved)
  auto asrc = [&](int t) { return (t % 3 == 1) ? xl : xh; };
  auto acol = [&](int t) { return (t / 3) * 64; };
#define SA(t, par, h) stage_half(asrc(t), 2048, m0 + (h)*128, acol(t), &sA[par][(h)*8192], w, l)
#define SB(t, par, h) stage_half(bt, KP, n0 + (h)*128, (t)*64, &sB[par][(h)*8192], w, l)

  f32x4 acc[8][4];
#pragma unroll
  for (int i = 0; i < 8; ++i)
#pragma unroll
    for (int j = 0; j < 4; ++j) acc[i][j] = (f32x4){0.f, 0.f, 0.f, 0.f};
  bf16x8 bfr[4][2];

  // prologue: B(0), A(0) must land; B(1) may stay in flight (4 loads) -> vmcnt(4)
  SB(0, 0, 0); SB(0, 0, 1);
  SA(0, 0, 0); SA(0, 0, 1);
  SB(1, 1, 0); SB(1, 1, 1);
  VMW4();
  BAR();

  auto nostage = [] {};
#pragma unroll 1
  for (int i = 0; i < 47; ++i) {               // tiles 0..93
    const int t1 = 2 * i + 1, tb = 2 * i + 2, tb2 = 2 * i + 3;
    // phases 0-3: compute tile 2i (buf0); stages: A(t1)->bufA1, B(tb)->bufB0
    do_phase<0>(sA[0], sB[0], acc, bfr, wr, wc, l15, l4, [&] { SA(t1, 1, 0); }, false, false);
    do_phase<1>(sA[0], sB[0], acc, bfr, wr, wc, l15, l4, [&] { SA(t1, 1, 1); }, false, false);
    do_phase<2>(sA[0], sB[0], acc, bfr, wr, wc, l15, l4, [&] { SB(tb, 0, 0); }, false, false);
    do_phase<3>(sA[0], sB[0], acc, bfr, wr, wc, l15, l4, [&] { SB(tb, 0, 1); }, true, false);
    // phases 4-7: compute tile 2i+1 (buf1); stages: A(tb)->bufA0, B(tb2)->bufB1
    do_phase<0>(sA[1], sB[1], acc, bfr, wr, wc, l15, l4, [&] { SA(tb, 0, 0); }, false, false);
    do_phase<1>(sA[1], sB[1], acc, bfr, wr, wc, l15, l4, [&] { SA(tb, 0, 1); }, false, false);
    do_phase<2>(sA[1], sB[1], acc, bfr, wr, wc, l15, l4, [&] { SB(tb2, 1, 0); }, false, false);
    do_phase<3>(sA[1], sB[1], acc, bfr, wr, wc, l15, l4, [&] { SB(tb2, 1, 1); }, true, false);
  }
  // tail: tiles 94 (buf0) and 95 (buf1); only A(95) still needs staging
  do_phase<0>(sA[0], sB[0], acc, bfr, wr, wc, l15, l4, [&] { SA(95, 1, 0); }, false, false);
  do_phase<1>(sA[0], sB[0], acc, bfr, wr, wc, l15, l4, [&] { SA(95, 1, 1); }, false, false);
  do_phase<2>(sA[0], sB[0], acc, bfr, wr, wc, l15, l4, nostage, false, false);
  do_phase<3>(sA[0], sB[0], acc, bfr, wr, wc, l15, l4, nostage, false, true);
  do_phase<0>(sA[1], sB[1], acc, bfr, wr, wc, l15, l4, nostage, false, false);
  do_phase<1>(sA[1], sB[1], acc, bfr, wr, wc, l15, l4, nostage, false, false);
  do_phase<2>(sA[1], sB[1], acc, bfr, wr, wc, l15, l4, nostage, false, false);
  do_phase<3>(sA[1], sB[1], acc, bfr, wr, wc, l15, l4, nostage, false, false);
#undef SA
#undef SB

  // epilogue: bias -> ELU -> BN; C/D layout: col=l&15, row=(l>>4)*4+r
  const int r0 = l4 * 4;
#pragma unroll
  for (int nf = 0; nf < 4; ++nf) {
    const int col = n0 + wc * 64 + nf * 16 + l15;
    const float sv = gamma[col] * rsqrtf(var[col] + BN_EPS);
    const float tv = beta[col] - mean[col] * sv;
    const float bv = bias[col];
#pragma unroll
    for (int mf = 0; mf < 8; ++mf) {
      const int row = m0 + wr * 128 + mf * 16 + r0;
#pragma unroll
      for (int r = 0; r < 4; ++r) {
        float v = acc[mf][nf][r] + bv;
        v = v > 0.f ? v : (expf(v) - 1.f);
        out[(size_t)(row + r) * NOUT + col] = fmaf(v, sv, tv);
      }
    }
  }
}

// ---------- fallback (no workspace): fp32 vector path, correct but slow ----------
__global__ void naive_kernel(const float* __restrict__ x, const float* __restrict__ adj,
                             const float* __restrict__ W, const float* __restrict__ bias,
                             const float* __restrict__ gamma, const float* __restrict__ beta,
                             const float* __restrict__ mean, const float* __restrict__ var,
                             float* __restrict__ out) {
  __shared__ float A[NCH * NCH];
  int t = threadIdx.x;
  if (t < NCH * NCH) {
    int i = t / NCH, j = t % NCH;
    float di = 0.f, dj = 0.f;
    for (int q = 0; q < NCH; ++q) {
      di += fabsf(adj[i * NCH + q]);
      dj += fabsf(adj[j * NCH + q]);
    }
    di = fmaxf(di, 1e-8f);
    dj = fmaxf(dj, 1e-8f);
    A[t] = adj[i * NCH + j] * rsqrtf(di * dj) + (i == j ? 1.f : 0.f);
  }
  __syncthreads();
  int idx = blockIdx.x * blockDim.x + threadIdx.x;
  int b = idx >> 11, o = idx & (NOUT - 1);
  const float* xb = x + (size_t)b * (NCH * FEAT);
  float sup[NCH];
#pragma unroll
  for (int j = 0; j < NCH; ++j) sup[j] = 0.f;
  for (int f = 0; f < FEAT; ++f) {
    float wv = W[(size_t)f * NOUT + o];
#pragma unroll
    for (int j = 0; j < NCH; ++j) sup[j] = fmaf(xb[j * FEAT + f], wv, sup[j]);
  }
  float sv = gamma[o] * rsqrtf(var[o] + BN_EPS);
  float tv = beta[o] - mean[o] * sv;
  float bv = bias[o];
#pragma unroll
  for (int i = 0; i < NCH; ++i) {
    float v = bv;
#pragma unroll
    for (int j = 0; j < NCH; ++j) v = fmaf(A[i * NCH + j], sup[j], v);
    v = v > 0.f ? v : (expf(v) - 1.f);
    out[((size_t)b * NCH + i) * NOUT + o] = v * sv + tv;
  }
}

extern "C" void kernel_launch(void* const* d_in, const int* in_sizes, int n_in,
                              void* d_out, int out_size, void* d_ws, size_t ws_size,
                              hipStream_t stream) {
  const float* x     = (const float*)d_in[0];
  const float* adj   = (const float*)d_in[1];
  const float* W     = (const float*)d_in[2];
  const float* bias  = (const float*)d_in[3];
  const float* gamma = (const float*)d_in[4];
  const float* beta  = (const float*)d_in[5];
  const float* mean  = (const float*)d_in[6];
  const float* var   = (const float*)d_in[7];
  float* out = (float*)d_out;

  const size_t XH_OFF = 0;                        // 160 MB
  const size_t XL_OFF = 167772160ull;             // 160 MB
  const size_t BT_OFF = XL_OFF + 167772160ull;    // 24 MB
  const size_t WS_NEED = BT_OFF + 25165824ull;    // ~344 MB

  if (ws_size >= WS_NEED) {
    char* ws = (char*)d_ws;
    u16* xhp = (u16*)(ws + XH_OFF);
    u16* xlp = (u16*)(ws + XL_OFF);
    u16* btp = (u16*)(ws + BT_OFF);
    hipLaunchKernelGGL(prep_b_kernel, dim3(64, 64), dim3(32, 8), 0, stream, W, btp);
    hipLaunchKernelGGL(premix_kernel, dim3(BATCH), dim3(256), 0, stream, x, adj, xhp, xlp);
    hipLaunchKernelGGL(gemm_kernel, dim3((MROWS / 256) * (NOUT / 256)), dim3(512), 0, stream,
                       xhp, xlp, btp, bias, gamma, beta, mean, var, out);
  } else {
    hipLaunchKernelGGL(naive_kernel, dim3((BATCH * NOUT) / 256), dim3(256), 0, stream,
                       x, adj, W, bias, gamma, beta, mean, var, out);
  }
}